// Round 5
// baseline (817.226 us; speedup 1.0000x reference)
//
#include <hip/hip_runtime.h>
#include <hip/hip_bf16.h>

#define R_REL 2016
#define MROWS 16384
#define HDIM  1024
#define EDIM  768
#define TOPK  28
#define KSEL  32
#define CAP   64
#define NPAD  2048
#define MPADR 2048   // rel rows padded

typedef unsigned short u16;
typedef __attribute__((ext_vector_type(8))) short short8;
typedef __attribute__((ext_vector_type(4))) float f32x4;

__device__ inline float bf2f(u16 u) {
  unsigned x = ((unsigned)u) << 16; float f;
  __builtin_memcpy(&f, &x, 4); return f;
}
__device__ inline u16 f2bf(float f) {
  __hip_bfloat16 h = __float2bfloat16(f);
  u16 u; __builtin_memcpy(&u, &h, 2); return u;
}
__device__ inline void gl2lds16(const void* g, void* l) {
  __builtin_amdgcn_global_load_lds((const __attribute__((address_space(1))) unsigned int*)g,
                                   (__attribute__((address_space(3))) unsigned int*)l, 16, 0, 0);
}

// ================= bf16x3 (or x1) NT GEMM, 64x64 tile, 4 waves ==================
// C[m,n] = sum_k A[m,k]*B[n,k] (+bias[n]); A planes [Mpad,K], B planes [Npad,K].
// PLANES=3: h/m/l split-precision (~f32 accuracy). PLANES=1: plain bf16.
template<int PLANES>
__global__ __launch_bounds__(256) void x3gemm(
    const u16* __restrict__ Ah, const u16* __restrict__ Am, const u16* __restrict__ Al,
    const u16* __restrict__ Bh, const u16* __restrict__ Bm, const u16* __restrict__ Bl,
    const float* __restrict__ bias, float* __restrict__ C,
    int K, int Nstride, int Mlim, int Nlim)
{
  __shared__ u16 lA[PLANES][64 * 32];
  __shared__ u16 lB[PLANES][64 * 32];
  const u16* Ap[3] = {Ah, Am, Al};
  const u16* Bp[3] = {Bh, Bm, Bl};
  const int tid = threadIdx.x;
  const int wave = tid >> 6, lane = tid & 63;
  const int wr = wave >> 1, wc = wave & 1;
  const int row0 = blockIdx.y * 64, col0 = blockIdx.x * 64;

  f32x4 acc[2][2];
#pragma unroll
  for (int m = 0; m < 2; ++m)
#pragma unroll
    for (int n = 0; n < 2; ++n) acc[m][n] = (f32x4){0.f, 0.f, 0.f, 0.f};

  const int srow = lane >> 2, sslot = lane & 3;
  const int r15 = lane & 15, kq = lane >> 4;

  for (int k0 = 0; k0 < K; k0 += 32) {
    const int row = wave * 16 + srow;
    const int kg = sslot ^ ((row >> 1) & 3);   // inverse-swizzled global col-block
#pragma unroll
    for (int p = 0; p < PLANES; ++p) {
      gl2lds16(Ap[p] + (size_t)(row0 + row) * K + k0 + kg * 8, (u16*)lA[p] + wave * 512);
      gl2lds16(Bp[p] + (size_t)(col0 + row) * K + k0 + kg * 8, (u16*)lB[p] + wave * 512);
    }
    __syncthreads();
    short8 a[PLANES][2], b[PLANES][2];
#pragma unroll
    for (int m = 0; m < 2; ++m) {
      const int rowL = wr * 32 + m * 16 + r15;
      const int slot = kq ^ ((rowL >> 1) & 3);
#pragma unroll
      for (int p = 0; p < PLANES; ++p)
        a[p][m] = *reinterpret_cast<const short8*>(&lA[p][rowL * 32 + slot * 8]);
    }
#pragma unroll
    for (int n = 0; n < 2; ++n) {
      const int colL = wc * 32 + n * 16 + r15;
      const int slot = kq ^ ((colL >> 1) & 3);
#pragma unroll
      for (int p = 0; p < PLANES; ++p)
        b[p][n] = *reinterpret_cast<const short8*>(&lB[p][colL * 32 + slot * 8]);
    }
#pragma unroll
    for (int m = 0; m < 2; ++m)
#pragma unroll
      for (int n = 0; n < 2; ++n) {
        if constexpr (PLANES == 3) {
          acc[m][n] = __builtin_amdgcn_mfma_f32_16x16x32_bf16(a[2][m], b[0][n], acc[m][n], 0, 0, 0);
          acc[m][n] = __builtin_amdgcn_mfma_f32_16x16x32_bf16(a[0][m], b[2][n], acc[m][n], 0, 0, 0);
          acc[m][n] = __builtin_amdgcn_mfma_f32_16x16x32_bf16(a[1][m], b[1][n], acc[m][n], 0, 0, 0);
          acc[m][n] = __builtin_amdgcn_mfma_f32_16x16x32_bf16(a[1][m], b[0][n], acc[m][n], 0, 0, 0);
          acc[m][n] = __builtin_amdgcn_mfma_f32_16x16x32_bf16(a[0][m], b[1][n], acc[m][n], 0, 0, 0);
          acc[m][n] = __builtin_amdgcn_mfma_f32_16x16x32_bf16(a[0][m], b[0][n], acc[m][n], 0, 0, 0);
        } else {
          acc[m][n] = __builtin_amdgcn_mfma_f32_16x16x32_bf16(a[0][m], b[0][n], acc[m][n], 0, 0, 0);
        }
      }
    __syncthreads();
  }
  const int quad = lane >> 4;
#pragma unroll
  for (int m = 0; m < 2; ++m)
#pragma unroll
    for (int n = 0; n < 2; ++n) {
      const int cg = col0 + wc * 32 + n * 16 + r15;
      if (cg >= Nlim) continue;
      const float ev = bias ? bias[cg] : 0.f;
#pragma unroll
      for (int reg = 0; reg < 4; ++reg) {
        const int rg = row0 + wr * 32 + m * 16 + quad * 4 + reg;
        if (rg < Mlim) C[(size_t)rg * Nstride + cg] = acc[m][n][reg] + ev;
      }
    }
}

// ============ scores MFMA (128x128, BK=32, XCD-swizzled): Kt = key((A@B^T + cvec)/32) ======
__global__ __launch_bounds__(256) void mfma_scores128(
    const u16* __restrict__ A, const u16* __restrict__ B,
    const float* __restrict__ cvec, u16* __restrict__ Kt, int K, int Nlim)
{
  __shared__ u16 ldsA[128 * 32];
  __shared__ u16 ldsB[128 * 32];
  const int tid = threadIdx.x;
  const int wave = tid >> 6, lane = tid & 63;
  const int wr = wave >> 1, wc = wave & 1;
  // bijective XCD chunk swizzle (nwg % 8 == 0)
  unsigned wg = blockIdx.y * gridDim.x + blockIdx.x;
  const unsigned per = (gridDim.x * gridDim.y) >> 3;
  wg = (wg & 7) * per + (wg >> 3);
  const int row0 = (int)(wg / gridDim.x) * 128, col0 = (int)(wg % gridDim.x) * 128;

  f32x4 acc[4][4];
#pragma unroll
  for (int m = 0; m < 4; ++m)
#pragma unroll
    for (int n = 0; n < 4; ++n) acc[m][n] = (f32x4){0.f, 0.f, 0.f, 0.f};

  const int srow = lane >> 2, sslot = lane & 3;

  for (int k0 = 0; k0 < K; k0 += 32) {
#pragma unroll
    for (int j = 0; j < 2; ++j) {
      const int row = (wave * 2 + j) * 16 + srow;
      const int kg = sslot ^ ((row >> 1) & 3);
      gl2lds16(A + (size_t)(row0 + row) * K + k0 + kg * 8, (char*)ldsA + (size_t)(wave * 2 + j) * 1024);
      gl2lds16(B + (size_t)(col0 + row) * K + k0 + kg * 8, (char*)ldsB + (size_t)(wave * 2 + j) * 1024);
    }
    __syncthreads();
    const int r15 = lane & 15, kq = lane >> 4;
    short8 a[4], b[4];
#pragma unroll
    for (int m = 0; m < 4; ++m) {
      const int rowL = wr * 64 + m * 16 + r15;
      const int slot = kq ^ ((rowL >> 1) & 3);
      a[m] = *reinterpret_cast<const short8*>(&ldsA[rowL * 32 + slot * 8]);
    }
#pragma unroll
    for (int n = 0; n < 4; ++n) {
      const int colL = wc * 64 + n * 16 + r15;
      const int slot = kq ^ ((colL >> 1) & 3);
      b[n] = *reinterpret_cast<const short8*>(&ldsB[colL * 32 + slot * 8]);
    }
#pragma unroll
    for (int m = 0; m < 4; ++m)
#pragma unroll
      for (int n = 0; n < 4; ++n)
        acc[m][n] = __builtin_amdgcn_mfma_f32_16x16x32_bf16(a[m], b[n], acc[m][n], 0, 0, 0);
    __syncthreads();
  }
  const int r15 = lane & 15, quad = lane >> 4;
#pragma unroll
  for (int m = 0; m < 4; ++m)
#pragma unroll
    for (int n = 0; n < 4; ++n) {
      const int cg = col0 + wc * 64 + n * 16 + r15;
      if (cg >= Nlim) continue;
      const float cv = cvec[cg];
#pragma unroll
      for (int reg = 0; reg < 4; ++reg) {
        const int rg = row0 + wr * 64 + m * 16 + quad * 4 + reg;
        const float s = (acc[m][n][reg] + cv) * 0.03125f;
        const u16 u = f2bf(s);
        const u16 key = (u & 0x8000) ? (u16)(~u) : (u16)(u | 0x8000);
        Kt[(size_t)rg * NPAD + cg] = key;
      }
    }
}

// ================= decompose / transpose / conv helpers =================
// f32 -> 3 bf16 planes (exact splits), zero-pad beyond n4_valid (leading-contiguous valid)
__global__ __launch_bounds__(256) void decompose3(
    const float* __restrict__ in, u16* __restrict__ H, u16* __restrict__ M, u16* __restrict__ L,
    long n4_total, long n4_valid)
{
  for (long i = blockIdx.x * 256 + threadIdx.x; i < n4_total; i += (long)gridDim.x * 256) {
    u16 oh[4] = {0,0,0,0}, om[4] = {0,0,0,0}, ol[4] = {0,0,0,0};
    if (i < n4_valid) {
      const float4 f = *reinterpret_cast<const float4*>(in + i * 4);
      const float xs[4] = {f.x, f.y, f.z, f.w};
#pragma unroll
      for (int t = 0; t < 4; ++t) {
        const float x = xs[t];
        const u16 h = f2bf(x);       const float r1 = x - bf2f(h);
        const u16 m = f2bf(r1);      const float r2 = r1 - bf2f(m);
        const u16 l = f2bf(r2);
        oh[t] = h; om[t] = m; ol[t] = l;
      }
    }
    *reinterpret_cast<ulong1*>(H + i * 4) = *reinterpret_cast<ulong1*>(oh);
    *reinterpret_cast<ulong1*>(M + i * 4) = *reinterpret_cast<ulong1*>(om);
    *reinterpret_cast<ulong1*>(L + i * 4) = *reinterpret_cast<ulong1*>(ol);
  }
}

// in [R,C] f32 -> transposed planes [C,R] bf16 x3. R,C multiples of 32.
__global__ __launch_bounds__(256) void decomposeT(
    const float* __restrict__ in, u16* __restrict__ H, u16* __restrict__ M, u16* __restrict__ L,
    int R, int C)
{
  __shared__ float t[32][33];
  const int x = threadIdx.x & 31, y = threadIdx.x >> 5;
  const int bx = blockIdx.x, by = blockIdx.y;   // bx over C/32, by over R/32
#pragma unroll
  for (int yy = 0; yy < 4; ++yy)
    t[y + yy * 8][x] = in[(size_t)(by * 32 + y + yy * 8) * C + bx * 32 + x];
  __syncthreads();
#pragma unroll
  for (int yy = 0; yy < 4; ++yy) {
    const float v = t[x][y + yy * 8];
    const u16 h = f2bf(v);      const float r1 = v - bf2f(h);
    const u16 m = f2bf(r1);     const float r2 = r1 - bf2f(m);
    const u16 l = f2bf(r2);
    const size_t o = (size_t)(bx * 32 + y + yy * 8) * R + by * 32 + x;
    H[o] = h; M[o] = m; L[o] = l;
  }
}

__global__ __launch_bounds__(256) void conv_bf16_pad(
    const float* __restrict__ in, u16* __restrict__ out, long n4_total, long n4_valid)
{
  for (long i = blockIdx.x * 256 + threadIdx.x; i < n4_total; i += (long)gridDim.x * 256) {
    u16 o[4] = {0, 0, 0, 0};
    if (i < n4_valid) {
      const float4 f = *reinterpret_cast<const float4*>(in + i * 4);
      o[0] = f2bf(f.x); o[1] = f2bf(f.y); o[2] = f2bf(f.z); o[3] = f2bf(f.w);
    }
    *reinterpret_cast<ulong1*>(out + i * 4) = *reinterpret_cast<ulong1*>(o);
  }
}

// out[j] = sum_k A[j*sj + k*sk] * v[k]  (+ addvec[j]) (+ *addscal); wave per row
__global__ __launch_bounds__(256) void rowdot(
    const float* __restrict__ A, long sj, long sk, const float* __restrict__ v,
    const float* __restrict__ addvec, const float* __restrict__ addscal,
    float* __restrict__ out, int R, int K)
{
  const int row = blockIdx.x * 4 + (threadIdx.x >> 6);
  const int lane = threadIdx.x & 63;
  if (row >= R) return;
  float acc = 0.f;
  for (int k = lane; k < K; k += 64)
    acc = fmaf(A[(size_t)row * sj + (size_t)k * sk], v[k], acc);
#pragma unroll
  for (int off = 32; off; off >>= 1) acc += __shfl_xor(acc, off);
  if (lane == 0) {
    float r = acc;
    if (addvec) r += addvec[row];
    if (addscal) r += *addscal;
    out[row] = r;
  }
}

// ================= mask / misc =================
__global__ void detect_mask_kind(const unsigned int* __restrict__ m, int* __restrict__ flag) {
  if (threadIdx.x == 0 && blockIdx.x == 0) {
    int kind = 0; bool saw_gt1 = false;
    for (int i = 0; i < 256; ++i) {
      unsigned w = m[i];
      if (w == 0x3F800000u) { kind = 2; saw_gt1 = false; break; }
      if (w > 1u) saw_gt1 = true;
    }
    if (kind != 2 && saw_gt1) kind = 1;
    *flag = kind;
  }
}

__global__ __launch_bounds__(256) void build_fbits(
    const void* __restrict__ mask, const int* __restrict__ kind,
    unsigned long long* __restrict__ fbits)
{
  const int gm = blockIdx.x * 4 + (threadIdx.x >> 6);
  const int lane = threadIdx.x & 63;
  const int k = *kind;
  const size_t e = (size_t)gm * 64 + lane;
  bool on;
  if (k == 0)      on = ((const int*)mask)[e] != 0;
  else if (k == 1) on = ((const unsigned char*)mask)[e] != 0;
  else             on = ((const float*)mask)[e] != 0.f;
  const unsigned long long b = __ballot(on);
  if (lane == 0) fbits[gm] = b;
}

__global__ void fij_pack_k(const int* __restrict__ f_i, const int* __restrict__ f_j,
                           unsigned* __restrict__ fij) {
  const int i = blockIdx.x * 256 + threadIdx.x;
  if (i < NPAD) {
    const int src = (i < R_REL) ? i : (R_REL - 1);
    fij[i] = ((unsigned)f_i[src] & 0xFFFFu) | (((unsigned)f_j[src] & 0xFFFFu) << 16);
  }
}

// ====== radix prefilter + ILP-4 exact f32 rescore + bitonic top-28 + softmax ======
__global__ __launch_bounds__(64) void topk_radix(
    const u16* __restrict__ Kt, const unsigned long long* __restrict__ fbits,
    const unsigned* __restrict__ fij,
    const float* __restrict__ qh, const float* __restrict__ W2, const float* __restrict__ cvec,
    int* __restrict__ topidx, float* __restrict__ topw)
{
  const int gm = blockIdx.x;
  const int lane = threadIdx.x;
  const unsigned long long fb = fbits[gm];
  __shared__ int cand[CAP];

  unsigned key[32];
  const u16* rowp = Kt + (size_t)gm * NPAD;
#pragma unroll
  for (int L = 0; L < 4; ++L) {
    const int rrb = lane * 8 + L * 512;
    const short8 v = *reinterpret_cast<const short8*>(rowp + rrb);
    const uint4 p0 = *reinterpret_cast<const uint4*>(fij + rrb);
    const uint4 p1 = *reinterpret_cast<const uint4*>(fij + rrb + 4);
    const unsigned ps[8] = {p0.x, p0.y, p0.z, p0.w, p1.x, p1.y, p1.z, p1.w};
#pragma unroll
    for (int r = 0; r < 8; ++r) {
      const int rr = rrb + r;
      const unsigned p = ps[r];
      const bool act = (rr < R_REL) &&
        ((((fb >> (p & 63u)) & (fb >> (p >> 16))) & 1ULL) != 0);
      key[L * 8 + r] = act ? (unsigned)(u16)v[r] : 0u;
    }
  }

  // binary search largest T with count(key >= T) >= KSEL
  int lo = 1, hi = 65536;
  while (hi - lo > 1) {
    const int mid = (lo + hi) >> 1;
    int cnt = 0;
#pragma unroll
    for (int j = 0; j < 32; ++j)
      cnt += __popcll(__ballot(key[j] >= (unsigned)mid));
    if (cnt >= KSEL) lo = mid; else hi = mid;
  }
  const unsigned T = (unsigned)lo;

  // extract candidates (deterministic order), capped at CAP
  int base = 0;
#pragma unroll
  for (int L = 0; L < 4; ++L) {
#pragma unroll
    for (int r = 0; r < 8; ++r) {
      const int j = L * 8 + r;
      const bool c = key[j] >= T;
      const unsigned long long m = __ballot(c);
      const int pre = __builtin_amdgcn_mbcnt_hi((unsigned)(m >> 32),
                      __builtin_amdgcn_mbcnt_lo((unsigned)m, 0));
      const int slot = base + pre;
      if (c && slot < CAP) cand[slot] = lane * 8 + r + L * 512;
      base += __popcll(m);
    }
  }
  const int ncand = (base < CAP) ? base : CAP;
  __syncthreads();

  // exact f32 rescore, 4 candidates per iteration (ILP)
  float q[16];
  {
    const float* qp = qh + (size_t)gm * HDIM + lane * 16;
#pragma unroll
    for (int v4 = 0; v4 < 4; ++v4) {
      const float4 f = *reinterpret_cast<const float4*>(qp + v4 * 4);
      q[v4 * 4 + 0] = f.x; q[v4 * 4 + 1] = f.y; q[v4 * 4 + 2] = f.z; q[v4 * 4 + 3] = f.w;
    }
  }
  float myscore = -INFINITY;
  for (int c = 0; c < CAP; c += 4) {
    if (c >= ncand) break;
    int rr4[4];
#pragma unroll
    for (int t = 0; t < 4; ++t) rr4[t] = (c + t < ncand) ? cand[c + t] : cand[0];
    float d0 = 0.f, d1 = 0.f, d2 = 0.f, d3 = 0.f;
#pragma unroll
    for (int v4 = 0; v4 < 4; ++v4) {
      const float4 f0 = *reinterpret_cast<const float4*>(W2 + (size_t)rr4[0] * HDIM + lane * 16 + v4 * 4);
      const float4 f1 = *reinterpret_cast<const float4*>(W2 + (size_t)rr4[1] * HDIM + lane * 16 + v4 * 4);
      const float4 f2 = *reinterpret_cast<const float4*>(W2 + (size_t)rr4[2] * HDIM + lane * 16 + v4 * 4);
      const float4 f3 = *reinterpret_cast<const float4*>(W2 + (size_t)rr4[3] * HDIM + lane * 16 + v4 * 4);
      d0 = fmaf(q[v4*4+0], f0.x, d0); d0 = fmaf(q[v4*4+1], f0.y, d0);
      d0 = fmaf(q[v4*4+2], f0.z, d0); d0 = fmaf(q[v4*4+3], f0.w, d0);
      d1 = fmaf(q[v4*4+0], f1.x, d1); d1 = fmaf(q[v4*4+1], f1.y, d1);
      d1 = fmaf(q[v4*4+2], f1.z, d1); d1 = fmaf(q[v4*4+3], f1.w, d1);
      d2 = fmaf(q[v4*4+0], f2.x, d2); d2 = fmaf(q[v4*4+1], f2.y, d2);
      d2 = fmaf(q[v4*4+2], f2.z, d2); d2 = fmaf(q[v4*4+3], f2.w, d2);
      d3 = fmaf(q[v4*4+0], f3.x, d3); d3 = fmaf(q[v4*4+1], f3.y, d3);
      d3 = fmaf(q[v4*4+2], f3.z, d3); d3 = fmaf(q[v4*4+3], f3.w, d3);
    }
#pragma unroll
    for (int off = 32; off; off >>= 1) {
      d0 += __shfl_xor(d0, off); d1 += __shfl_xor(d1, off);
      d2 += __shfl_xor(d2, off); d3 += __shfl_xor(d3, off);
    }
    const float dd[4] = {d0, d1, d2, d3};
#pragma unroll
    for (int t = 0; t < 4; ++t)
      if (c + t < ncand && lane == c + t) myscore = (dd[t] + cvec[rr4[t]]) * 0.03125f;
  }
  int myr = 0x7fffffff;
  if (lane < ncand) myr = cand[lane];

  // bitonic sort 64 lanes, descending score, tie -> ascending index
#pragma unroll
  for (int k = 2; k <= 64; k <<= 1) {
#pragma unroll
    for (int j = k >> 1; j > 0; j >>= 1) {
      const float ov = __shfl_xor(myscore, j);
      const int oi = __shfl_xor(myr, j);
      const bool lower = (lane & j) == 0;
      const bool want_desc = (lane & k) == 0;
      const bool mine_better = (myscore > ov) || (myscore == ov && myr < oi);
      const bool keep = (lower == want_desc) ? mine_better : !mine_better;
      if (!keep) { myscore = ov; myr = oi; }
    }
  }

  const int nvalid = __popcll(__ballot(myscore > -INFINITY));
  const int nsel = (nvalid < TOPK) ? nvalid : TOPK;
  const float m0 = __shfl(myscore, 0);
  const float e = (lane < nsel) ? expf(myscore - m0) : 0.f;
  float z = e;
#pragma unroll
  for (int off = 32; off; off >>= 1) z += __shfl_xor(z, off);
  if (lane < TOPK) {
    topw[(size_t)gm * TOPK + lane] = (lane < nsel) ? (e / z) : 0.f;
    topidx[(size_t)gm * TOPK + lane] = (lane < nsel) ? myr : 0;
  }
}

__global__ __launch_bounds__(256) void out_gather(
    const int* __restrict__ topidx, const float* __restrict__ topw,
    const float* __restrict__ V, float* __restrict__ out)
{
  const int gm = blockIdx.x;
  const int tid = threadIdx.x;
  __shared__ float w[TOPK];
  __shared__ int   id[TOPK];
  if (tid < TOPK) {
    w[tid] = topw[(size_t)gm * TOPK + tid];
    id[tid] = topidx[(size_t)gm * TOPK + tid];
  }
  __syncthreads();
  float4 acc = make_float4(0.f, 0.f, 0.f, 0.f);
#pragma unroll 4
  for (int i = 0; i < TOPK; ++i) {
    const float wi = w[i];
    const float4 v = *reinterpret_cast<const float4*>(V + (size_t)id[i] * HDIM + tid * 4);
    acc.x = fmaf(wi, v.x, acc.x);
    acc.y = fmaf(wi, v.y, acc.y);
    acc.z = fmaf(wi, v.z, acc.z);
    acc.w = fmaf(wi, v.w, acc.w);
  }
  *reinterpret_cast<float4*>(out + (size_t)gm * HDIM + tid * 4) = acc;
}

extern "C" void kernel_launch(void* const* d_in, const int* in_sizes, int n_in,
                              void* d_out, int out_size, void* d_ws, size_t ws_size,
                              hipStream_t stream) {
  const float* qh  = (const float*)d_in[0];
  const void*  mask = d_in[1];
  const float* rel = (const float*)d_in[2];
  const int* f_i = (const int*)d_in[3];
  const int* f_j = (const int*)d_in[4];
  const float* Wt = (const float*)d_in[5]; const float* bt = (const float*)d_in[6];
  const float* Wq = (const float*)d_in[7]; const float* bq = (const float*)d_in[8];
  const float* Wk = (const float*)d_in[9]; const float* bk = (const float*)d_in[10];
  const float* Wv = (const float*)d_in[11]; const float* bv = (const float*)d_in[12];
  float* out = (float*)d_out;

  // ---- workspace layout with lifetime-based aliasing (~152 MB) ----
  char* p = (char*)d_ws;
  auto alloc = [&](size_t bytes) { char* q_ = p; p += (bytes + 255) & ~(size_t)255; return q_; };
  float* W2   = (float*)alloc((size_t)R_REL * HDIM * 4);
  // scratch f32 strip: T1f | Pf | Pvf ; later aliased by Vm
  char* strip = alloc((size_t)(1024*1024 + 1024*768 + 1024*768) * 4);
  float* T1f = (float*)strip;
  float* Pf  = T1f + 1024 * 1024;
  float* Pvf = Pf + 1024 * 768;
  float* Vm  = (float*)strip;                   // alias (written after T1f/Pf/Pvf dead)
  // plane regions (u16): R1 = WqT -> T1 -> Wv ; R2 = WkT -> P
  u16* R1 = (u16*)alloc((size_t)3 * 1024 * 1024 * 2);
  u16* R2 = (u16*)alloc((size_t)3 * 1024 * 1024 * 2);
  u16* WtTp = (u16*)alloc((size_t)3 * 768 * 1024 * 2);
  u16* relp = (u16*)alloc((size_t)3 * MPADR * EDIM * 2);
  u16* qhb  = (u16*)alloc((size_t)MROWS * HDIM * 2);
  char* w2b_region = alloc((size_t)NPAD * HDIM * 2);
  u16* W2b  = (u16*)w2b_region;
  u16* Pv16 = (u16*)alloc((size_t)1024 * 768 * 2);
  u16* Kt   = (u16*)alloc((size_t)MROWS * NPAD * 2);
  float* cvec   = (float*)alloc(NPAD * 4);
  float* u1     = (float*)alloc(1024 * 4);
  float* u2     = (float*)alloc(1024 * 4);
  float* w2tmp  = (float*)alloc(1024 * 4);
  float* w2bias = (float*)alloc(1024 * 4);
  float* cvv    = (float*)alloc(1024 * 4);
  float* c0a    = (float*)alloc(256);
  float* c0     = (float*)alloc(256);
  unsigned long long* fbits = (unsigned long long*)alloc((size_t)MROWS * 8);
  unsigned* fij = (unsigned*)alloc(NPAD * 4);
  int* kindflag = (int*)alloc(256);
  int* tidx = (int*)w2b_region;                           // alias (W2b dead before topk)
  float* tw = (float*)(w2b_region + (size_t)MROWS * TOPK * 4);

  const size_t PL1 = (size_t)1024 * 1024;   // 1024x1024 plane elems
  const size_t PLW = (size_t)768 * 1024;    // WtT plane elems
  const size_t PLR = (size_t)MPADR * EDIM;  // rel plane elems
  const size_t PLP = (size_t)1024 * 768;    // P/Pv plane elems

  const dim3 blk(256);

  // masks / misc
  detect_mask_kind<<<1, 64, 0, stream>>>((const unsigned int*)mask, kindflag);
  build_fbits<<<dim3(MROWS / 4), blk, 0, stream>>>(mask, kindflag, fbits);
  fij_pack_k<<<dim3(NPAD / 256), blk, 0, stream>>>(f_i, f_j, fij);

  // weight decompositions
  decomposeT<<<dim3(1024/32, 1024/32), blk, 0, stream>>>(Wq, R1, R1+PL1, R1+2*PL1, 1024, 1024);
  decomposeT<<<dim3(1024/32, 1024/32), blk, 0, stream>>>(Wk, R2, R2+PL1, R2+2*PL1, 1024, 1024);
  decomposeT<<<dim3(768/32, 1024/32), blk, 0, stream>>>(Wt, WtTp, WtTp+PLW, WtTp+2*PLW, 1024, 768);
  decompose3<<<dim3(1024), blk, 0, stream>>>(rel, relp, relp+PLR, relp+2*PLR,
                                             (long)MPADR*EDIM/4, (long)R_REL*EDIM/4);

  // bias vector chains (tiny)
  rowdot<<<dim3(256), blk, 0, stream>>>(Wk, 1, 1024, bq, nullptr, nullptr, u1, 1024, 1024);
  rowdot<<<dim3(192), blk, 0, stream>>>(Wt, 1, 768, u1, nullptr, nullptr, u2, 768, 1024);
  rowdot<<<dim3(1), blk, 0, stream>>>(bt, 0, 1, u1, nullptr, nullptr, c0a, 1, 1024);
  rowdot<<<dim3(1), blk, 0, stream>>>(bk, 0, 1, bq, nullptr, c0a, c0, 1, 1024);
  rowdot<<<dim3((R_REL + 3) / 4), blk, 0, stream>>>(rel, EDIM, 1, u2, nullptr, c0, cvec, R_REL, EDIM);
  rowdot<<<dim3(256), blk, 0, stream>>>(Wv, 1024, 1, bt, bv, nullptr, cvv, 1024, 1024);

  // T1 = Wq^T @ Wk  (bf16x3, ~f32 exact)
  x3gemm<3><<<dim3(1024/64, 1024/64), blk, 0, stream>>>(
      R1, R1+PL1, R1+2*PL1, R2, R2+PL1, R2+2*PL1, nullptr, T1f, 1024, 1024, 1024, 1024);
  // w2bias[j] = bt@(Wk^T Wq)[.,j] + bk@Wq[.,j] = T1f[j,:]·bt + Wq[:,j]·bk
  rowdot<<<dim3(256), blk, 0, stream>>>(T1f, 1024, 1, bt, nullptr, nullptr, w2tmp, 1024, 1024);
  rowdot<<<dim3(256), blk, 0, stream>>>(Wq, 1, 1024, bk, w2tmp, nullptr, w2bias, 1024, 1024);
  // T1 planes (overwrite R1)
  decompose3<<<dim3(1024), blk, 0, stream>>>(T1f, R1, R1+PL1, R1+2*PL1, (long)PL1/4, (long)PL1/4);
  // P = T1 @ Wt  ->  [1024,768]
  x3gemm<3><<<dim3(768/64, 1024/64), blk, 0, stream>>>(
      R1, R1+PL1, R1+2*PL1, WtTp, WtTp+PLW, WtTp+2*PLW, nullptr, Pf, 1024, 768, 1024, 768);
  // P planes (overwrite R2)
  decompose3<<<dim3(1024), blk, 0, stream>>>(Pf, R2, R2+PLP, R2+2*PLP, (long)PLP/4, (long)PLP/4);
  // Wv planes (overwrite R1) ; Pv = Wv @ Wt -> [1024,768]
  decompose3<<<dim3(1024), blk, 0, stream>>>(Wv, R1, R1+PL1, R1+2*PL1, (long)PL1/4, (long)PL1/4);
  x3gemm<3><<<dim3(768/64, 1024/64), blk, 0, stream>>>(
      R1, R1+PL1, R1+2*PL1, WtTp, WtTp+PLW, WtTp+2*PLW, nullptr, Pvf, 1024, 768, 1024, 768);
  // W2 = rel @ P^T + w2bias  -> [2016,1024]  (bf16x3 exact chain)
  x3gemm<3><<<dim3(1024/64, MPADR/64), blk, 0, stream>>>(
      relp, relp+PLR, relp+2*PLR, R2, R2+PLP, R2+2*PLP, w2bias, W2, EDIM, HDIM, R_REL, HDIM);

  // bf16 copies for prefilter / Vm
  conv_bf16_pad<<<dim3(2048), blk, 0, stream>>>(qh, qhb, (long)MROWS*HDIM/4, (long)MROWS*HDIM/4);
  conv_bf16_pad<<<dim3(512), blk, 0, stream>>>(W2, W2b, (long)NPAD*HDIM/4, (long)R_REL*HDIM/4);
  conv_bf16_pad<<<dim3(512), blk, 0, stream>>>(Pvf, Pv16, (long)PLP/4, (long)PLP/4);

  // approx score keys
  mfma_scores128<<<dim3(NPAD/128, MROWS/128), blk, 0, stream>>>(qhb, W2b, cvec, Kt, HDIM, R_REL);

  // Vm = rel_h @ Pv16^T + cvv  (bf16; aliases the dead f32 strip)
  x3gemm<1><<<dim3(1024/64, MPADR/64), blk, 0, stream>>>(
      relp, nullptr, nullptr, Pv16, nullptr, nullptr, cvv, Vm, EDIM, HDIM, R_REL, HDIM);

  // prefilter + exact rescore + top-28 + softmax
  topk_radix<<<dim3(MROWS), dim3(64), 0, stream>>>(Kt, fbits, fij, qh, W2, cvec, tidx, tw);

  out_gather<<<dim3(MROWS), blk, 0, stream>>>(tidx, tw, Vm, out);
}

// Round 6
// 662.080 us; speedup vs baseline: 1.2343x; 1.2343x over previous
//
#include <hip/hip_runtime.h>
#include <hip/hip_bf16.h>

#define R_REL 2016
#define MROWS 16384
#define HDIM  1024
#define EDIM  768
#define TOPK  28
#define KSEL  31
#define CAP   48
#define NPAD  2048
#define MPADR 2048   // rel rows padded

typedef unsigned short u16;
typedef __attribute__((ext_vector_type(8))) short short8;
typedef __attribute__((ext_vector_type(4))) float f32x4;

__device__ inline float bf2f(u16 u) {
  unsigned x = ((unsigned)u) << 16; float f;
  __builtin_memcpy(&f, &x, 4); return f;
}
__device__ inline u16 f2bf(float f) {
  __hip_bfloat16 h = __float2bfloat16(f);
  u16 u; __builtin_memcpy(&u, &h, 2); return u;
}
__device__ inline void gl2lds16(const void* g, void* l) {
  __builtin_amdgcn_global_load_lds((const __attribute__((address_space(1))) unsigned int*)g,
                                   (__attribute__((address_space(3))) unsigned int*)l, 16, 0, 0);
}

// ================= bf16x3 (or x1) NT GEMM, 64x64 tile, 4 waves ==================
template<int PLANES>
__global__ __launch_bounds__(256) void x3gemm(
    const u16* __restrict__ Ah, const u16* __restrict__ Am, const u16* __restrict__ Al,
    const u16* __restrict__ Bh, const u16* __restrict__ Bm, const u16* __restrict__ Bl,
    const float* __restrict__ bias, float* __restrict__ C,
    int K, int Nstride, int Mlim, int Nlim)
{
  __shared__ u16 lA[PLANES][64 * 32];
  __shared__ u16 lB[PLANES][64 * 32];
  const u16* Ap[3] = {Ah, Am, Al};
  const u16* Bp[3] = {Bh, Bm, Bl};
  const int tid = threadIdx.x;
  const int wave = tid >> 6, lane = tid & 63;
  const int wr = wave >> 1, wc = wave & 1;
  const int row0 = blockIdx.y * 64, col0 = blockIdx.x * 64;

  f32x4 acc[2][2];
#pragma unroll
  for (int m = 0; m < 2; ++m)
#pragma unroll
    for (int n = 0; n < 2; ++n) acc[m][n] = (f32x4){0.f, 0.f, 0.f, 0.f};

  const int srow = lane >> 2, sslot = lane & 3;
  const int r15 = lane & 15, kq = lane >> 4;

  for (int k0 = 0; k0 < K; k0 += 32) {
    const int row = wave * 16 + srow;
    const int kg = sslot ^ ((row >> 1) & 3);
#pragma unroll
    for (int p = 0; p < PLANES; ++p) {
      gl2lds16(Ap[p] + (size_t)(row0 + row) * K + k0 + kg * 8, (u16*)lA[p] + wave * 512);
      gl2lds16(Bp[p] + (size_t)(col0 + row) * K + k0 + kg * 8, (u16*)lB[p] + wave * 512);
    }
    __syncthreads();
    short8 a[PLANES][2], b[PLANES][2];
#pragma unroll
    for (int m = 0; m < 2; ++m) {
      const int rowL = wr * 32 + m * 16 + r15;
      const int slot = kq ^ ((rowL >> 1) & 3);
#pragma unroll
      for (int p = 0; p < PLANES; ++p)
        a[p][m] = *reinterpret_cast<const short8*>(&lA[p][rowL * 32 + slot * 8]);
    }
#pragma unroll
    for (int n = 0; n < 2; ++n) {
      const int colL = wc * 32 + n * 16 + r15;
      const int slot = kq ^ ((colL >> 1) & 3);
#pragma unroll
      for (int p = 0; p < PLANES; ++p)
        b[p][n] = *reinterpret_cast<const short8*>(&lB[p][colL * 32 + slot * 8]);
    }
#pragma unroll
    for (int m = 0; m < 2; ++m)
#pragma unroll
      for (int n = 0; n < 2; ++n) {
        if constexpr (PLANES == 3) {
          acc[m][n] = __builtin_amdgcn_mfma_f32_16x16x32_bf16(a[2][m], b[0][n], acc[m][n], 0, 0, 0);
          acc[m][n] = __builtin_amdgcn_mfma_f32_16x16x32_bf16(a[0][m], b[2][n], acc[m][n], 0, 0, 0);
          acc[m][n] = __builtin_amdgcn_mfma_f32_16x16x32_bf16(a[1][m], b[1][n], acc[m][n], 0, 0, 0);
          acc[m][n] = __builtin_amdgcn_mfma_f32_16x16x32_bf16(a[1][m], b[0][n], acc[m][n], 0, 0, 0);
          acc[m][n] = __builtin_amdgcn_mfma_f32_16x16x32_bf16(a[0][m], b[1][n], acc[m][n], 0, 0, 0);
          acc[m][n] = __builtin_amdgcn_mfma_f32_16x16x32_bf16(a[0][m], b[0][n], acc[m][n], 0, 0, 0);
        } else {
          acc[m][n] = __builtin_amdgcn_mfma_f32_16x16x32_bf16(a[0][m], b[0][n], acc[m][n], 0, 0, 0);
        }
      }
    __syncthreads();
  }
  const int quad = lane >> 4;
#pragma unroll
  for (int m = 0; m < 2; ++m)
#pragma unroll
    for (int n = 0; n < 2; ++n) {
      const int cg = col0 + wc * 32 + n * 16 + r15;
      if (cg >= Nlim) continue;
      const float ev = bias ? bias[cg] : 0.f;
#pragma unroll
      for (int reg = 0; reg < 4; ++reg) {
        const int rg = row0 + wr * 32 + m * 16 + quad * 4 + reg;
        if (rg < Mlim) C[(size_t)rg * Nstride + cg] = acc[m][n][reg] + ev;
      }
    }
}

// ============ scores MFMA (128x128, BK=32, XCD-swizzled): Kt = key((A@B^T + cvec)/32) ======
__global__ __launch_bounds__(256) void mfma_scores128(
    const u16* __restrict__ A, const u16* __restrict__ B,
    const float* __restrict__ cvec, u16* __restrict__ Kt, int K, int Nlim)
{
  __shared__ u16 ldsA[128 * 32];
  __shared__ u16 ldsB[128 * 32];
  const int tid = threadIdx.x;
  const int wave = tid >> 6, lane = tid & 63;
  const int wr = wave >> 1, wc = wave & 1;
  unsigned wg = blockIdx.y * gridDim.x + blockIdx.x;
  const unsigned per = (gridDim.x * gridDim.y) >> 3;
  wg = (wg & 7) * per + (wg >> 3);
  const int row0 = (int)(wg / gridDim.x) * 128, col0 = (int)(wg % gridDim.x) * 128;

  f32x4 acc[4][4];
#pragma unroll
  for (int m = 0; m < 4; ++m)
#pragma unroll
    for (int n = 0; n < 4; ++n) acc[m][n] = (f32x4){0.f, 0.f, 0.f, 0.f};

  const int srow = lane >> 2, sslot = lane & 3;

  for (int k0 = 0; k0 < K; k0 += 32) {
#pragma unroll
    for (int j = 0; j < 2; ++j) {
      const int row = (wave * 2 + j) * 16 + srow;
      const int kg = sslot ^ ((row >> 1) & 3);
      gl2lds16(A + (size_t)(row0 + row) * K + k0 + kg * 8, (char*)ldsA + (size_t)(wave * 2 + j) * 1024);
      gl2lds16(B + (size_t)(col0 + row) * K + k0 + kg * 8, (char*)ldsB + (size_t)(wave * 2 + j) * 1024);
    }
    __syncthreads();
    const int r15 = lane & 15, kq = lane >> 4;
    short8 a[4], b[4];
#pragma unroll
    for (int m = 0; m < 4; ++m) {
      const int rowL = wr * 64 + m * 16 + r15;
      const int slot = kq ^ ((rowL >> 1) & 3);
      a[m] = *reinterpret_cast<const short8*>(&ldsA[rowL * 32 + slot * 8]);
    }
#pragma unroll
    for (int n = 0; n < 4; ++n) {
      const int colL = wc * 64 + n * 16 + r15;
      const int slot = kq ^ ((colL >> 1) & 3);
      b[n] = *reinterpret_cast<const short8*>(&ldsB[colL * 32 + slot * 8]);
    }
#pragma unroll
    for (int m = 0; m < 4; ++m)
#pragma unroll
      for (int n = 0; n < 4; ++n)
        acc[m][n] = __builtin_amdgcn_mfma_f32_16x16x32_bf16(a[m], b[n], acc[m][n], 0, 0, 0);
    __syncthreads();
  }
  const int r15 = lane & 15, quad = lane >> 4;
#pragma unroll
  for (int m = 0; m < 4; ++m)
#pragma unroll
    for (int n = 0; n < 4; ++n) {
      const int cg = col0 + wc * 64 + n * 16 + r15;
      if (cg >= Nlim) continue;
      const float cv = cvec[cg];
#pragma unroll
      for (int reg = 0; reg < 4; ++reg) {
        const int rg = row0 + wr * 64 + m * 16 + quad * 4 + reg;
        const float s = (acc[m][n][reg] + cv) * 0.03125f;
        const u16 u = f2bf(s);
        const u16 key = (u & 0x8000) ? (u16)(~u) : (u16)(u | 0x8000);
        Kt[(size_t)rg * NPAD + cg] = key;
      }
    }
}

// ================= decompose / transpose / conv helpers =================
__global__ __launch_bounds__(256) void decompose3(
    const float* __restrict__ in, u16* __restrict__ H, u16* __restrict__ M, u16* __restrict__ L,
    long n4_total, long n4_valid)
{
  for (long i = blockIdx.x * 256 + threadIdx.x; i < n4_total; i += (long)gridDim.x * 256) {
    u16 oh[4] = {0,0,0,0}, om[4] = {0,0,0,0}, ol[4] = {0,0,0,0};
    if (i < n4_valid) {
      const float4 f = *reinterpret_cast<const float4*>(in + i * 4);
      const float xs[4] = {f.x, f.y, f.z, f.w};
#pragma unroll
      for (int t = 0; t < 4; ++t) {
        const float x = xs[t];
        const u16 h = f2bf(x);       const float r1 = x - bf2f(h);
        const u16 m = f2bf(r1);      const float r2 = r1 - bf2f(m);
        const u16 l = f2bf(r2);
        oh[t] = h; om[t] = m; ol[t] = l;
      }
    }
    *reinterpret_cast<ulong1*>(H + i * 4) = *reinterpret_cast<ulong1*>(oh);
    *reinterpret_cast<ulong1*>(M + i * 4) = *reinterpret_cast<ulong1*>(om);
    *reinterpret_cast<ulong1*>(L + i * 4) = *reinterpret_cast<ulong1*>(ol);
  }
}

__global__ __launch_bounds__(256) void decomposeT(
    const float* __restrict__ in, u16* __restrict__ H, u16* __restrict__ M, u16* __restrict__ L,
    int R, int C)
{
  __shared__ float t[32][33];
  const int x = threadIdx.x & 31, y = threadIdx.x >> 5;
  const int bx = blockIdx.x, by = blockIdx.y;
#pragma unroll
  for (int yy = 0; yy < 4; ++yy)
    t[y + yy * 8][x] = in[(size_t)(by * 32 + y + yy * 8) * C + bx * 32 + x];
  __syncthreads();
#pragma unroll
  for (int yy = 0; yy < 4; ++yy) {
    const float v = t[x][y + yy * 8];
    const u16 h = f2bf(v);      const float r1 = v - bf2f(h);
    const u16 m = f2bf(r1);     const float r2 = r1 - bf2f(m);
    const u16 l = f2bf(r2);
    const size_t o = (size_t)(bx * 32 + y + yy * 8) * R + by * 32 + x;
    H[o] = h; M[o] = m; L[o] = l;
  }
}

__global__ __launch_bounds__(256) void conv_bf16_pad(
    const float* __restrict__ in, u16* __restrict__ out, long n4_total, long n4_valid)
{
  for (long i = blockIdx.x * 256 + threadIdx.x; i < n4_total; i += (long)gridDim.x * 256) {
    u16 o[4] = {0, 0, 0, 0};
    if (i < n4_valid) {
      const float4 f = *reinterpret_cast<const float4*>(in + i * 4);
      o[0] = f2bf(f.x); o[1] = f2bf(f.y); o[2] = f2bf(f.z); o[3] = f2bf(f.w);
    }
    *reinterpret_cast<ulong1*>(out + i * 4) = *reinterpret_cast<ulong1*>(o);
  }
}

__global__ __launch_bounds__(256) void rowdot(
    const float* __restrict__ A, long sj, long sk, const float* __restrict__ v,
    const float* __restrict__ addvec, const float* __restrict__ addscal,
    float* __restrict__ out, int R, int K)
{
  const int row = blockIdx.x * 4 + (threadIdx.x >> 6);
  const int lane = threadIdx.x & 63;
  if (row >= R) return;
  float acc = 0.f;
  for (int k = lane; k < K; k += 64)
    acc = fmaf(A[(size_t)row * sj + (size_t)k * sk], v[k], acc);
#pragma unroll
  for (int off = 32; off; off >>= 1) acc += __shfl_xor(acc, off);
  if (lane == 0) {
    float r = acc;
    if (addvec) r += addvec[row];
    if (addscal) r += *addscal;
    out[row] = r;
  }
}

// ================= mask / misc =================
__global__ void detect_mask_kind(const unsigned int* __restrict__ m, int* __restrict__ flag) {
  if (threadIdx.x == 0 && blockIdx.x == 0) {
    int kind = 0; bool saw_gt1 = false;
    for (int i = 0; i < 256; ++i) {
      unsigned w = m[i];
      if (w == 0x3F800000u) { kind = 2; saw_gt1 = false; break; }
      if (w > 1u) saw_gt1 = true;
    }
    if (kind != 2 && saw_gt1) kind = 1;
    *flag = kind;
  }
}

__global__ __launch_bounds__(256) void build_fbits(
    const void* __restrict__ mask, const int* __restrict__ kind,
    unsigned long long* __restrict__ fbits)
{
  const int gm = blockIdx.x * 4 + (threadIdx.x >> 6);
  const int lane = threadIdx.x & 63;
  const int k = *kind;
  const size_t e = (size_t)gm * 64 + lane;
  bool on;
  if (k == 0)      on = ((const int*)mask)[e] != 0;
  else if (k == 1) on = ((const unsigned char*)mask)[e] != 0;
  else             on = ((const float*)mask)[e] != 0.f;
  const unsigned long long b = __ballot(on);
  if (lane == 0) fbits[gm] = b;
}

__global__ void fij_pack_k(const int* __restrict__ f_i, const int* __restrict__ f_j,
                           unsigned* __restrict__ fij) {
  const int i = blockIdx.x * 256 + threadIdx.x;
  if (i < NPAD) {
    const int src = (i < R_REL) ? i : (R_REL - 1);
    fij[i] = ((unsigned)f_i[src] & 0xFFFFu) | (((unsigned)f_j[src] & 0xFFFFu) << 16);
  }
}

// ====== radix prefilter + SERIAL exact f32 rescore + bitonic top-28 + softmax ======
__global__ __launch_bounds__(64) void topk_radix(
    const u16* __restrict__ Kt, const unsigned long long* __restrict__ fbits,
    const unsigned* __restrict__ fij,
    const float* __restrict__ qh, const float* __restrict__ W2, const float* __restrict__ cvec,
    int* __restrict__ topidx, float* __restrict__ topw)
{
  const int gm = blockIdx.x;
  const int lane = threadIdx.x;
  const unsigned long long fb = fbits[gm];
  __shared__ int cand[CAP];

  unsigned key[32];
  const u16* rowp = Kt + (size_t)gm * NPAD;
#pragma unroll
  for (int L = 0; L < 4; ++L) {
    const int rrb = lane * 8 + L * 512;
    const short8 v = *reinterpret_cast<const short8*>(rowp + rrb);
    const uint4 p0 = *reinterpret_cast<const uint4*>(fij + rrb);
    const uint4 p1 = *reinterpret_cast<const uint4*>(fij + rrb + 4);
    const unsigned ps[8] = {p0.x, p0.y, p0.z, p0.w, p1.x, p1.y, p1.z, p1.w};
#pragma unroll
    for (int r = 0; r < 8; ++r) {
      const int rr = rrb + r;
      const unsigned p = ps[r];
      const bool act = (rr < R_REL) &&
        ((((fb >> (p & 63u)) & (fb >> (p >> 16))) & 1ULL) != 0);
      key[L * 8 + r] = act ? (unsigned)(u16)v[r] : 0u;
    }
  }

  // binary search largest T with count(key >= T) >= KSEL
  int lo = 1, hi = 65536;
  while (hi - lo > 1) {
    const int mid = (lo + hi) >> 1;
    int cnt = 0;
#pragma unroll
    for (int j = 0; j < 32; ++j)
      cnt += __popcll(__ballot(key[j] >= (unsigned)mid));
    if (cnt >= KSEL) lo = mid; else hi = mid;
  }
  const unsigned T = (unsigned)lo;

  // extract candidates (deterministic order), capped at CAP
  int base = 0;
#pragma unroll
  for (int L = 0; L < 4; ++L) {
#pragma unroll
    for (int r = 0; r < 8; ++r) {
      const int j = L * 8 + r;
      const bool c = key[j] >= T;
      const unsigned long long m = __ballot(c);
      const int pre = __builtin_amdgcn_mbcnt_hi((unsigned)(m >> 32),
                      __builtin_amdgcn_mbcnt_lo((unsigned)m, 0));
      const int slot = base + pre;
      if (c && slot < CAP) cand[slot] = lane * 8 + r + L * 512;
      base += __popcll(m);
    }
  }
  const int ncand = (base < CAP) ? base : CAP;
  __syncthreads();

  // exact f32 rescore, one candidate at a time (L1 keeps the row across v4 steps)
  float q[16];
  {
    const float* qp = qh + (size_t)gm * HDIM + lane * 16;
#pragma unroll
    for (int v4 = 0; v4 < 4; ++v4) {
      const float4 f = *reinterpret_cast<const float4*>(qp + v4 * 4);
      q[v4 * 4 + 0] = f.x; q[v4 * 4 + 1] = f.y; q[v4 * 4 + 2] = f.z; q[v4 * 4 + 3] = f.w;
    }
  }
  float myscore = -INFINITY;
  for (int c = 0; c < CAP; ++c) {
    if (c >= ncand) break;
    const int r = cand[c];
    const float* wp = W2 + (size_t)r * HDIM + lane * 16;
    float d = 0.f;
#pragma unroll
    for (int v4 = 0; v4 < 4; ++v4) {
      const float4 f = *reinterpret_cast<const float4*>(wp + v4 * 4);
      d = fmaf(q[v4 * 4 + 0], f.x, d);
      d = fmaf(q[v4 * 4 + 1], f.y, d);
      d = fmaf(q[v4 * 4 + 2], f.z, d);
      d = fmaf(q[v4 * 4 + 3], f.w, d);
    }
#pragma unroll
    for (int off = 32; off; off >>= 1) d += __shfl_xor(d, off);
    const float s = (d + cvec[r]) * 0.03125f;
    if (lane == c) myscore = s;
  }
  int myr = 0x7fffffff;
  if (lane < ncand) myr = cand[lane];

  // bitonic sort 64 lanes, descending score, tie -> ascending index
#pragma unroll
  for (int k = 2; k <= 64; k <<= 1) {
#pragma unroll
    for (int j = k >> 1; j > 0; j >>= 1) {
      const float ov = __shfl_xor(myscore, j);
      const int oi = __shfl_xor(myr, j);
      const bool lower = (lane & j) == 0;
      const bool want_desc = (lane & k) == 0;
      const bool mine_better = (myscore > ov) || (myscore == ov && myr < oi);
      const bool keep = (lower == want_desc) ? mine_better : !mine_better;
      if (!keep) { myscore = ov; myr = oi; }
    }
  }

  const int nvalid = __popcll(__ballot(myscore > -INFINITY));
  const int nsel = (nvalid < TOPK) ? nvalid : TOPK;
  const float m0 = __shfl(myscore, 0);
  const float e = (lane < nsel) ? expf(myscore - m0) : 0.f;
  float z = e;
#pragma unroll
  for (int off = 32; off; off >>= 1) z += __shfl_xor(z, off);
  if (lane < TOPK) {
    topw[(size_t)gm * TOPK + lane] = (lane < nsel) ? (e / z) : 0.f;
    topidx[(size_t)gm * TOPK + lane] = (lane < nsel) ? myr : 0;
  }
}

__global__ __launch_bounds__(256) void out_gather(
    const int* __restrict__ topidx, const float* __restrict__ topw,
    const float* __restrict__ V, float* __restrict__ out)
{
  const int gm = blockIdx.x;
  const int tid = threadIdx.x;
  __shared__ float w[TOPK];
  __shared__ int   id[TOPK];
  if (tid < TOPK) {
    w[tid] = topw[(size_t)gm * TOPK + tid];
    id[tid] = topidx[(size_t)gm * TOPK + tid];
  }
  __syncthreads();
  float4 acc = make_float4(0.f, 0.f, 0.f, 0.f);
#pragma unroll 4
  for (int i = 0; i < TOPK; ++i) {
    const float wi = w[i];
    const float4 v = *reinterpret_cast<const float4*>(V + (size_t)id[i] * HDIM + tid * 4);
    acc.x = fmaf(wi, v.x, acc.x);
    acc.y = fmaf(wi, v.y, acc.y);
    acc.z = fmaf(wi, v.z, acc.z);
    acc.w = fmaf(wi, v.w, acc.w);
  }
  *reinterpret_cast<float4*>(out + (size_t)gm * HDIM + tid * 4) = acc;
}

extern "C" void kernel_launch(void* const* d_in, const int* in_sizes, int n_in,
                              void* d_out, int out_size, void* d_ws, size_t ws_size,
                              hipStream_t stream) {
  const float* qh  = (const float*)d_in[0];
  const void*  mask = d_in[1];
  const float* rel = (const float*)d_in[2];
  const int* f_i = (const int*)d_in[3];
  const int* f_j = (const int*)d_in[4];
  const float* Wt = (const float*)d_in[5]; const float* bt = (const float*)d_in[6];
  const float* Wq = (const float*)d_in[7]; const float* bq = (const float*)d_in[8];
  const float* Wk = (const float*)d_in[9]; const float* bk = (const float*)d_in[10];
  const float* Wv = (const float*)d_in[11]; const float* bv = (const float*)d_in[12];
  float* out = (float*)d_out;

  // ---- workspace layout with lifetime-based aliasing ----
  char* p = (char*)d_ws;
  auto alloc = [&](size_t bytes) { char* q_ = p; p += (bytes + 255) & ~(size_t)255; return q_; };
  float* W2   = (float*)alloc((size_t)R_REL * HDIM * 4);
  char* strip = alloc((size_t)(1024*1024 + 1024*768 + 1024*768) * 4);
  float* T1f = (float*)strip;
  float* Pf  = T1f + 1024 * 1024;
  float* Pvf = Pf + 1024 * 768;
  float* Vm  = (float*)strip;                   // alias (written after T1f/Pf/Pvf dead)
  u16* R1 = (u16*)alloc((size_t)3 * 1024 * 1024 * 2);
  u16* R2 = (u16*)alloc((size_t)3 * 1024 * 1024 * 2);
  u16* WtTp = (u16*)alloc((size_t)3 * 768 * 1024 * 2);
  u16* relp = (u16*)alloc((size_t)3 * MPADR * EDIM * 2);
  u16* qhb  = (u16*)alloc((size_t)MROWS * HDIM * 2);
  char* w2b_region = alloc((size_t)NPAD * HDIM * 2);
  u16* W2b  = (u16*)w2b_region;
  u16* Pv16 = (u16*)alloc((size_t)1024 * 768 * 2);
  u16* Kt   = (u16*)alloc((size_t)MROWS * NPAD * 2);
  float* cvec   = (float*)alloc(NPAD * 4);
  float* u1     = (float*)alloc(1024 * 4);
  float* u2     = (float*)alloc(1024 * 4);
  float* w2tmp  = (float*)alloc(1024 * 4);
  float* w2bias = (float*)alloc(1024 * 4);
  float* cvv    = (float*)alloc(1024 * 4);
  float* c0a    = (float*)alloc(256);
  float* c0     = (float*)alloc(256);
  unsigned long long* fbits = (unsigned long long*)alloc((size_t)MROWS * 8);
  unsigned* fij = (unsigned*)alloc(NPAD * 4);
  int* kindflag = (int*)alloc(256);
  int* tidx = (int*)w2b_region;                           // alias (W2b dead before topk)
  float* tw = (float*)(w2b_region + (size_t)MROWS * TOPK * 4);

  const size_t PL1 = (size_t)1024 * 1024;
  const size_t PLW = (size_t)768 * 1024;
  const size_t PLR = (size_t)MPADR * EDIM;
  const size_t PLP = (size_t)1024 * 768;

  const dim3 blk(256);

  // masks / misc
  detect_mask_kind<<<1, 64, 0, stream>>>((const unsigned int*)mask, kindflag);
  build_fbits<<<dim3(MROWS / 4), blk, 0, stream>>>(mask, kindflag, fbits);
  fij_pack_k<<<dim3(NPAD / 256), blk, 0, stream>>>(f_i, f_j, fij);

  // weight decompositions
  decomposeT<<<dim3(1024/32, 1024/32), blk, 0, stream>>>(Wq, R1, R1+PL1, R1+2*PL1, 1024, 1024);
  decomposeT<<<dim3(1024/32, 1024/32), blk, 0, stream>>>(Wk, R2, R2+PL1, R2+2*PL1, 1024, 1024);
  decomposeT<<<dim3(768/32, 1024/32), blk, 0, stream>>>(Wt, WtTp, WtTp+PLW, WtTp+2*PLW, 1024, 768);
  decompose3<<<dim3(1024), blk, 0, stream>>>(rel, relp, relp+PLR, relp+2*PLR,
                                             (long)MPADR*EDIM/4, (long)R_REL*EDIM/4);

  // bias vector chains (tiny)
  rowdot<<<dim3(256), blk, 0, stream>>>(Wk, 1, 1024, bq, nullptr, nullptr, u1, 1024, 1024);
  rowdot<<<dim3(192), blk, 0, stream>>>(Wt, 1, 768, u1, nullptr, nullptr, u2, 768, 1024);
  rowdot<<<dim3(1), blk, 0, stream>>>(bt, 0, 1, u1, nullptr, nullptr, c0a, 1, 1024);
  rowdot<<<dim3(1), blk, 0, stream>>>(bk, 0, 1, bq, nullptr, c0a, c0, 1, 1024);
  rowdot<<<dim3((R_REL + 3) / 4), blk, 0, stream>>>(rel, EDIM, 1, u2, nullptr, c0, cvec, R_REL, EDIM);
  rowdot<<<dim3(256), blk, 0, stream>>>(Wv, 1024, 1, bt, bv, nullptr, cvv, 1024, 1024);

  // T1 = Wq^T @ Wk  (bf16x3)
  x3gemm<3><<<dim3(1024/64, 1024/64), blk, 0, stream>>>(
      R1, R1+PL1, R1+2*PL1, R2, R2+PL1, R2+2*PL1, nullptr, T1f, 1024, 1024, 1024, 1024);
  rowdot<<<dim3(256), blk, 0, stream>>>(T1f, 1024, 1, bt, nullptr, nullptr, w2tmp, 1024, 1024);
  rowdot<<<dim3(256), blk, 0, stream>>>(Wq, 1, 1024, bk, w2tmp, nullptr, w2bias, 1024, 1024);
  decompose3<<<dim3(1024), blk, 0, stream>>>(T1f, R1, R1+PL1, R1+2*PL1, (long)PL1/4, (long)PL1/4);
  // P = T1 @ Wt
  x3gemm<3><<<dim3(768/64, 1024/64), blk, 0, stream>>>(
      R1, R1+PL1, R1+2*PL1, WtTp, WtTp+PLW, WtTp+2*PLW, nullptr, Pf, 1024, 768, 1024, 768);
  decompose3<<<dim3(1024), blk, 0, stream>>>(Pf, R2, R2+PLP, R2+2*PLP, (long)PLP/4, (long)PLP/4);
  // Pv = Wv @ Wt
  decompose3<<<dim3(1024), blk, 0, stream>>>(Wv, R1, R1+PL1, R1+2*PL1, (long)PL1/4, (long)PL1/4);
  x3gemm<3><<<dim3(768/64, 1024/64), blk, 0, stream>>>(
      R1, R1+PL1, R1+2*PL1, WtTp, WtTp+PLW, WtTp+2*PLW, nullptr, Pvf, 1024, 768, 1024, 768);
  // W2 = rel @ P^T + w2bias
  x3gemm<3><<<dim3(1024/64, MPADR/64), blk, 0, stream>>>(
      relp, relp+PLR, relp+2*PLR, R2, R2+PLP, R2+2*PLP, w2bias, W2, EDIM, HDIM, R_REL, HDIM);

  // bf16 copies
  conv_bf16_pad<<<dim3(2048), blk, 0, stream>>>(qh, qhb, (long)MROWS*HDIM/4, (long)MROWS*HDIM/4);
  conv_bf16_pad<<<dim3(512), blk, 0, stream>>>(W2, W2b, (long)NPAD*HDIM/4, (long)R_REL*HDIM/4);
  conv_bf16_pad<<<dim3(512), blk, 0, stream>>>(Pvf, Pv16, (long)PLP/4, (long)PLP/4);

  // Vm = rel_h @ Pv16^T + cvv  (before scores, so Kt stays hot into topk)
  x3gemm<1><<<dim3(1024/64, MPADR/64), blk, 0, stream>>>(
      relp, nullptr, nullptr, Pv16, nullptr, nullptr, cvv, Vm, EDIM, HDIM, R_REL, HDIM);

  // approx score keys
  mfma_scores128<<<dim3(NPAD/128, MROWS/128), blk, 0, stream>>>(qhb, W2b, cvec, Kt, HDIM, R_REL);

  // prefilter + exact rescore + top-28 + softmax
  topk_radix<<<dim3(MROWS), dim3(64), 0, stream>>>(Kt, fbits, fij, qh, W2, cvec, tidx, tw);

  out_gather<<<dim3(MROWS), blk, 0, stream>>>(tidx, tw, Vm, out);
}